// Round 12
// baseline (850.705 us; speedup 1.0000x reference)
//
#include <hip/hip_runtime.h>
#include <hip/hip_bf16.h>

#define ND 128
#define ED 128
#define NIN 128
#define EIN 291
#define KPAD 320   // EIN padded to multiple of 32
#define HH 64
#define TM 32      // edges/nodes per block in embed/classify MFMA kernels
#define GSB 512    // grid blocks for step kernels (2 per CU)
#define MAXG 4     // max tiles (64 edges) per block per staging round

typedef __attribute__((ext_vector_type(8))) short short8;
typedef __attribute__((ext_vector_type(4))) float float4_;

__device__ __forceinline__ unsigned short f2bf(float f)
{
    union { float f; unsigned u; } v; v.f = f;
    unsigned u = v.u;
    unsigned r = (u + 0x7FFFu + ((u >> 16) & 1u)) >> 16;  // RNE
    return (unsigned short)r;
}
__device__ __forceinline__ float bf2f(unsigned short s)
{
    union { unsigned u; float f; } v; v.u = ((unsigned)s) << 16;
    return v.f;
}

// Stage T N-tiles x KC k-chunks of B (layout [col][K], bf16) into LDS in MFMA
// FRAGMENT ORDER: fragment f=tt*KC+kc occupies 64 consecutive short8 slots.
template<int T, int KC, int K>
__device__ __forceinline__ void stage_frags(const unsigned short* __restrict__ src,
                                            unsigned short* __restrict__ wreg,
                                            int t, int k0)
{
    constexpr int TOT = T * KC * 64;
#pragma unroll
    for (int it = 0; it < TOT / 256; it++) {
        int idx = it * 256 + t;
        int f = idx >> 6, l = idx & 63;
        int col = (f / KC) * 16 + (l & 15);
        int k = (f % KC) * 32 + ((l >> 4) * 8);
        *(short8*)&wreg[idx * 8] = *(const short8*)&src[(size_t)col * K + k0 + k];
    }
}
#define FRAG(wreg, f, lane) (*(const short8*)&(wreg)[(((f) << 6) + (lane)) * 8])

// Zero a float buffer.
__global__ __launch_bounds__(256) void zero_k(float* __restrict__ p, int n4)
{
    int idx = blockIdx.x * 256 + threadIdx.x;
    if (idx < n4) ((float4*)p)[idx] = make_float4(0.f, 0.f, 0.f, 0.f);
}

// Fused: convert fp32 accumulator -> bf16 activations, then zero the accumulator.
__global__ __launch_bounds__(256) void f2bfz_k(float* __restrict__ src,
                                               unsigned short* __restrict__ dst, int n4)
{
    int idx = blockIdx.x * 256 + threadIdx.x;
    if (idx < n4) {
        float4 v = ((const float4*)src)[idx];
        unsigned lo = (unsigned)f2bf(v.x) | ((unsigned)f2bf(v.y) << 16);
        unsigned hi = (unsigned)f2bf(v.z) | ((unsigned)f2bf(v.w) << 16);
        ((uint2*)dst)[idx] = make_uint2(lo, hi);
        ((float4*)src)[idx] = make_float4(0.f, 0.f, 0.f, 0.f);
    }
}

// One-time weight prep: transpose + fp32->bf16 (+ zero-pad K for edge-embed L1).
__global__ __launch_bounds__(256) void wprep_k(
    const float* __restrict__ mew0, const float* __restrict__ mew1, const float* __restrict__ mnw0,
    const float* __restrict__ eew0, const float* __restrict__ eew1, const float* __restrict__ cw0,
    const float* __restrict__ new0, const float* __restrict__ new1,
    unsigned short* __restrict__ w0T, unsigned short* __restrict__ w1T,
    unsigned short* __restrict__ wmT, unsigned short* __restrict__ w0eT,
    unsigned short* __restrict__ w1eT, unsigned short* __restrict__ cw0T,
    unsigned short* __restrict__ w0nT, unsigned short* __restrict__ w1nT)
{
    int idx = blockIdx.x * 256 + threadIdx.x;
    if (idx < 49152) {
        int c = idx / 768, k = idx % 768;
        w0T[idx] = f2bf(mew0[k * 64 + c]);
    } else if (idx < 57344) {
        int j = idx - 49152; int c = j / 64, k = j % 64;
        w1T[j] = f2bf(mew1[k * 128 + c]);
    } else if (idx < 106496) {
        int j = idx - 57344; int c = j / 384, k = j % 384;
        wmT[j] = f2bf(mnw0[k * 128 + c]);
    } else if (idx < 126976) {
        int j = idx - 106496; int c = j / KPAD, k = j % KPAD;
        w0eT[j] = (k < EIN) ? f2bf(eew0[k * 64 + c]) : (unsigned short)0;
    } else if (idx < 135168) {
        int j = idx - 126976; int c = j / 64, k = j % 64;
        w1eT[j] = f2bf(eew1[k * 128 + c]);
    } else if (idx < 143360) {
        int j = idx - 135168; int c = j / 128, k = j % 128;
        cw0T[j] = f2bf(cw0[k * 64 + c]);
    } else if (idx < 159744) {
        int j = idx - 143360; int c = j / 128, k = j % 128;
        w0nT[j] = f2bf(new0[k * 128 + c]);
    } else if (idx < 176128) {
        int j = idx - 159744; int c = j / 128, k = j % 128;
        w1nT[j] = f2bf(new1[k * 128 + c]);
    }
}

// MFMA node embed: 32 nodes/block (unchanged from r11).
__global__ __launch_bounds__(256) void node_embed_k(
    const float* __restrict__ x,
    const unsigned short* __restrict__ w0nT, const float* __restrict__ b0,
    const unsigned short* __restrict__ w1nT, const float* __restrict__ b1,
    unsigned short* __restrict__ nf0_bf, unsigned short* __restrict__ nf_bf, int N)
{
    const int t = threadIdx.x;
    const int n0 = blockIdx.x * TM;
    __shared__ unsigned short wreg[8192];
    __shared__ unsigned short xin[TM][130];
    __shared__ unsigned short h_bf[TM][130];

#pragma unroll
    for (int it = 0; it < 4; it++) {
        int idx = it * 256 + t;
        int r = idx >> 5, c4 = idx & 31;
        int node = n0 + r; if (node >= N) node = N - 1;
        float4 v = *(const float4*)(x + (size_t)node * NIN + c4 * 4);
        unsigned lo = (unsigned)f2bf(v.x) | ((unsigned)f2bf(v.y) << 16);
        unsigned hi = (unsigned)f2bf(v.z) | ((unsigned)f2bf(v.w) << 16);
        *(uint2*)&xin[r][c4 * 4] = make_uint2(lo, hi);
    }

    const int w = t >> 6, lane = t & 63, quad = lane >> 4, n16 = lane & 15;
    const int m = w & 1, nh = w >> 1;

    float4_ acc[4];
#pragma unroll
    for (int q = 0; q < 4; q++) acc[q] = (float4_){0.f, 0.f, 0.f, 0.f};
#pragma unroll
    for (int hf = 0; hf < 2; hf++) {
        stage_frags<8, 2, 128>(w0nT, wreg, t, hf * 64);
        __syncthreads();
#pragma unroll
        for (int kc = 0; kc < 2; kc++) {
            short8 a = *(const short8*)&xin[m * 16 + n16][hf * 64 + kc * 32 + quad * 8];
#pragma unroll
            for (int tt = 0; tt < 4; tt++) {
                short8 b = FRAG(wreg, (nh * 4 + tt) * 2 + kc, lane);
                acc[tt] = __builtin_amdgcn_mfma_f32_16x16x32_bf16(a, b, acc[tt], 0, 0, 0);
            }
        }
        __syncthreads();
    }
#pragma unroll
    for (int tt = 0; tt < 4; tt++) {
        int c = nh * 64 + tt * 16 + n16;
        float bias = b0[c];
#pragma unroll
        for (int r4 = 0; r4 < 4; r4++)
            h_bf[m * 16 + quad * 4 + r4][c] = f2bf(fmaxf(acc[tt][r4] + bias, 0.f));
    }
    __syncthreads();

    float4_ acc2[4];
#pragma unroll
    for (int q = 0; q < 4; q++) acc2[q] = (float4_){0.f, 0.f, 0.f, 0.f};
#pragma unroll
    for (int hf = 0; hf < 2; hf++) {
        stage_frags<8, 2, 128>(w1nT, wreg, t, hf * 64);
        __syncthreads();
#pragma unroll
        for (int kc = 0; kc < 2; kc++) {
            short8 a = *(const short8*)&h_bf[m * 16 + n16][hf * 64 + kc * 32 + quad * 8];
#pragma unroll
            for (int tt = 0; tt < 4; tt++) {
                short8 b = FRAG(wreg, (nh * 4 + tt) * 2 + kc, lane);
                acc2[tt] = __builtin_amdgcn_mfma_f32_16x16x32_bf16(a, b, acc2[tt], 0, 0, 0);
            }
        }
        __syncthreads();
    }
#pragma unroll
    for (int tt = 0; tt < 4; tt++) {
        int c = nh * 64 + tt * 16 + n16;
        float bias = b1[c];
#pragma unroll
        for (int r4 = 0; r4 < 4; r4++) {
            int row = m * 16 + quad * 4 + r4;
            int node = n0 + row;
            if (node < N) {
                unsigned short v = f2bf(acc2[tt][r4] + bias);
                nf0_bf[(size_t)node * ND + c] = v;
                nf_bf[(size_t)node * ND + c] = v;
            }
        }
    }
}

// MFMA edge embed: 32 edges/block (unchanged from r11).
__global__ __launch_bounds__(256) void edge_embed_k(
    const float* __restrict__ ea,
    const unsigned short* __restrict__ w0eT, const float* __restrict__ b0,
    const unsigned short* __restrict__ w1eT, const float* __restrict__ b1,
    unsigned short* __restrict__ ef0_bf, unsigned short* __restrict__ ef_bf, int E)
{
    const int t = threadIdx.x;
    const int e0 = blockIdx.x * TM;
    __shared__ unsigned short wreg[10240];
    __shared__ unsigned short ea_bf[TM][330];
    __shared__ unsigned short h_bf[TM][66];

#pragma unroll
    for (int it = 0; it < 10; it++) {
        int idx = it * 256 + t;
        int r = idx / 80, c4 = idx % 80;
        int e = e0 + r; if (e >= E) e = E - 1;
        const float* src = ea + (size_t)e * EIN + c4 * 4;
        int base = c4 * 4;
        float v0 = (base + 0 < EIN) ? src[0] : 0.f;
        float v1 = (base + 1 < EIN) ? src[1] : 0.f;
        float v2 = (base + 2 < EIN) ? src[2] : 0.f;
        float v3 = (base + 3 < EIN) ? src[3] : 0.f;
        unsigned lo = (unsigned)f2bf(v0) | ((unsigned)f2bf(v1) << 16);
        unsigned hi = (unsigned)f2bf(v2) | ((unsigned)f2bf(v3) << 16);
        *(uint2*)&ea_bf[r][base] = make_uint2(lo, hi);
    }

    const int w = t >> 6, lane = t & 63, quad = lane >> 4, n16 = lane & 15;
    const int m = w & 1, nh = w >> 1;

    float4_ accL[2];
    accL[0] = (float4_){0.f, 0.f, 0.f, 0.f}; accL[1] = accL[0];
#pragma unroll
    for (int hf = 0; hf < 2; hf++) {
        stage_frags<4, 5, KPAD>(w0eT, wreg, t, hf * 160);
        __syncthreads();
#pragma unroll
        for (int kc = 0; kc < 5; kc++) {
            short8 a = *(const short8*)&ea_bf[m * 16 + n16][hf * 160 + kc * 32 + quad * 8];
#pragma unroll
            for (int tt = 0; tt < 2; tt++) {
                short8 b = FRAG(wreg, (nh * 2 + tt) * 5 + kc, lane);
                accL[tt] = __builtin_amdgcn_mfma_f32_16x16x32_bf16(a, b, accL[tt], 0, 0, 0);
            }
        }
        __syncthreads();
    }
#pragma unroll
    for (int tt = 0; tt < 2; tt++) {
        int c = nh * 32 + tt * 16 + n16;
        float bias = b0[c];
#pragma unroll
        for (int r4 = 0; r4 < 4; r4++)
            h_bf[m * 16 + quad * 4 + r4][c] = f2bf(fmaxf(accL[tt][r4] + bias, 0.f));
    }
    __syncthreads();
    stage_frags<8, 2, 64>(w1eT, wreg, t, 0);
    __syncthreads();
    {
        float4_ acc[4];
#pragma unroll
        for (int q = 0; q < 4; q++) acc[q] = (float4_){0.f, 0.f, 0.f, 0.f};
#pragma unroll
        for (int kc = 0; kc < 2; kc++) {
            short8 a = *(const short8*)&h_bf[m * 16 + n16][kc * 32 + quad * 8];
#pragma unroll
            for (int tt = 0; tt < 4; tt++) {
                short8 b = FRAG(wreg, (nh * 4 + tt) * 2 + kc, lane);
                acc[tt] = __builtin_amdgcn_mfma_f32_16x16x32_bf16(a, b, acc[tt], 0, 0, 0);
            }
        }
#pragma unroll
        for (int tt = 0; tt < 4; tt++) {
            int c = nh * 64 + tt * 16 + n16;
            float bias = b1[c];
#pragma unroll
            for (int r4 = 0; r4 < 4; r4++) {
                int row = m * 16 + quad * 4 + r4;
                int e = e0 + row;
                if (e < E) {
                    unsigned short v = f2bf(acc[tt][r4] + bias);
                    ef0_bf[(size_t)e * ED + c] = v;
                    ef_bf[(size_t)e * ED + c] = v;
                }
            }
        }
    }
}

// STEP kernel A: edge-MLP L1 (768->64, ReLU) + L2 (64->128, ReLU), ef updated.
// Grid-stride: block handles tiles {bid + g*GSB}, g<MAXG. w1 persistent (16KB),
// w0 staged in three 32KB K-thirds, each serving all G tiles (acc in regs).
// L2 is per-wave (h C->A via private LDS slice, no barrier).
__global__ __launch_bounds__(256, 2) void step_a_k(
    const int* __restrict__ srcj, const int* __restrict__ tgti,
    const unsigned short* __restrict__ nf0_bf, const unsigned short* __restrict__ nf_bf,
    const unsigned short* __restrict__ ef0_bf, unsigned short* __restrict__ ef_bf,
    const unsigned short* __restrict__ w0T, const float* __restrict__ meb0,
    const unsigned short* __restrict__ w1T, const float* __restrict__ meb1,
    int E, int ntiles)
{
    const int t = threadIdx.x;
    __shared__ unsigned short w0reg[16384];   // 32 KB: one w0 K-third (frag order)
    __shared__ unsigned short w1reg[8192];    // 16 KB: w1 full (frag order)
    __shared__ unsigned short hsl[4][16 * 66];// per-wave h slice (C->A transform)

    const int w = t >> 6, lane = t & 63, quad = lane >> 4, n16 = lane & 15;

    stage_frags<8, 2, 64>(w1T, w1reg, t, 0);   // synced by first third's barrier

    int ng = 0;
    int tile[MAXG];
#pragma unroll
    for (int g = 0; g < MAXG; g++) {
        int tl = blockIdx.x + g * GSB;
        if (tl < ntiles) { tile[g] = tl; ng = g + 1; }
        else tile[g] = 0;
    }

    // per-tile A-row edge (lane supplies A row n16) and its i/j
    int ti[MAXG], sj[MAXG], ea_[MAXG];
#pragma unroll
    for (int g = 0; g < MAXG; g++) {
        if (g < ng) {
            int e = tile[g] * 64 + w * 16 + n16; if (e >= E) e = E - 1;
            ea_[g] = e; ti[g] = tgti[e]; sj[g] = srcj[e];
        }
    }

    float4_ acc[MAXG][4];
#pragma unroll
    for (int g = 0; g < MAXG; g++)
#pragma unroll
        for (int q = 0; q < 4; q++) acc[g][q] = (float4_){0.f, 0.f, 0.f, 0.f};

#pragma unroll
    for (int third = 0; third < 3; third++) {
        __syncthreads();
        stage_frags<4, 8, 768>(w0T, w0reg, t, third * 256);
        __syncthreads();
#pragma unroll
        for (int g = 0; g < MAXG; g++) {
            if (g < ng) {
                const unsigned short* s0;
                const unsigned short* s1;
                if (third == 0) { s0 = nf0_bf + (size_t)ti[g] * ND; s1 = nf_bf + (size_t)ti[g] * ND; }
                else if (third == 1) { s0 = nf0_bf + (size_t)sj[g] * ND; s1 = nf_bf + (size_t)sj[g] * ND; }
                else { s0 = ef0_bf + (size_t)ea_[g] * ED; s1 = ef_bf + (size_t)ea_[g] * ED; }
                short8 a[8];
#pragma unroll
                for (int k4 = 0; k4 < 4; k4++) {
                    a[k4]     = *(const short8*)(s0 + k4 * 32 + quad * 8);
                    a[4 + k4] = *(const short8*)(s1 + k4 * 32 + quad * 8);
                }
#pragma unroll
                for (int kc = 0; kc < 8; kc++)
#pragma unroll
                    for (int tt = 0; tt < 4; tt++)
                        acc[g][tt] = __builtin_amdgcn_mfma_f32_16x16x32_bf16(
                            a[kc], FRAG(w0reg, tt * 8 + kc, lane), acc[g][tt], 0, 0, 0);
            }
        }
    }

    // per-wave: bias+ReLU -> h slice (C layout), then L2 vs persistent w1
#pragma unroll
    for (int g = 0; g < MAXG; g++) {
        if (g < ng) {
#pragma unroll
            for (int tt = 0; tt < 4; tt++) {
                int c = tt * 16 + n16;
                float bias = meb0[c];
#pragma unroll
                for (int r4 = 0; r4 < 4; r4++)
                    hsl[w][(quad * 4 + r4) * 66 + c] = f2bf(fmaxf(acc[g][tt][r4] + bias, 0.f));
            }
            // wave-local LDS dependency; compiler inserts lgkmcnt wait
            float4_ acc2[8];
#pragma unroll
            for (int q = 0; q < 8; q++) acc2[q] = (float4_){0.f, 0.f, 0.f, 0.f};
#pragma unroll
            for (int kc = 0; kc < 2; kc++) {
                short8 a2 = *(const short8*)&hsl[w][n16 * 66 + kc * 32 + quad * 8];
#pragma unroll
                for (int tt = 0; tt < 8; tt++)
                    acc2[tt] = __builtin_amdgcn_mfma_f32_16x16x32_bf16(
                        a2, FRAG(w1reg, tt * 2 + kc, lane), acc2[tt], 0, 0, 0);
            }
#pragma unroll
            for (int tt = 0; tt < 8; tt++) {
                int c = tt * 16 + n16;
                float bias = meb1[c];
#pragma unroll
                for (int r4 = 0; r4 < 4; r4++) {
                    int e = tile[g] * 64 + w * 16 + quad * 4 + r4;
                    if (e < E)
                        ef_bf[(size_t)e * ED + c] = f2bf(fmaxf(acc2[tt][r4] + bias, 0.f));
                }
            }
        }
        __syncthreads();   // hsl reuse across g (all waves in step)
    }
}

// STEP kernel B: message MLP ([nf0_i|nf_i|ef] 384 -> 128, ReLU) + atomic scatter.
// wm staged in three 32KB K-thirds (third0=nf0_i, 1=nf_i, 2=ef), G tiles/round.
__global__ __launch_bounds__(256, 2) void step_b_k(
    const int* __restrict__ srcj, const int* __restrict__ tgti,
    const unsigned short* __restrict__ nf0_bf, const unsigned short* __restrict__ nf_bf,
    const unsigned short* __restrict__ ef_bf, float* __restrict__ nfn,
    const unsigned short* __restrict__ wmT, const float* __restrict__ mnb0,
    int E, int ntiles)
{
    const int t = threadIdx.x;
    __shared__ unsigned short wmreg[16384];   // 32 KB: one wm K-third (frag order)

    const int w = t >> 6, lane = t & 63, quad = lane >> 4, n16 = lane & 15;

    int ng = 0;
    int tile[MAXG];
#pragma unroll
    for (int g = 0; g < MAXG; g++) {
        int tl = blockIdx.x + g * GSB;
        if (tl < ntiles) { tile[g] = tl; ng = g + 1; }
        else tile[g] = 0;
    }

    int ti[MAXG], ea_[MAXG];
#pragma unroll
    for (int g = 0; g < MAXG; g++) {
        if (g < ng) {
            int e = tile[g] * 64 + w * 16 + n16; if (e >= E) e = E - 1;
            ea_[g] = e; ti[g] = tgti[e];
        }
    }

    float4_ acc[MAXG][8];
#pragma unroll
    for (int g = 0; g < MAXG; g++)
#pragma unroll
        for (int q = 0; q < 8; q++) acc[g][q] = (float4_){0.f, 0.f, 0.f, 0.f};

#pragma unroll
    for (int third = 0; third < 3; third++) {
        __syncthreads();
        stage_frags<8, 4, 384>(wmT, wmreg, t, third * 128);
        __syncthreads();
#pragma unroll
        for (int g = 0; g < MAXG; g++) {
            if (g < ng) {
                const unsigned short* s;
                if (third == 0)      s = nf0_bf + (size_t)ti[g] * ND;
                else if (third == 1) s = nf_bf + (size_t)ti[g] * ND;
                else                 s = ef_bf + (size_t)ea_[g] * ED;
                short8 a[4];
#pragma unroll
                for (int k4 = 0; k4 < 4; k4++)
                    a[k4] = *(const short8*)(s + k4 * 32 + quad * 8);
#pragma unroll
                for (int kc = 0; kc < 4; kc++)
#pragma unroll
                    for (int tt = 0; tt < 8; tt++)
                        acc[g][tt] = __builtin_amdgcn_mfma_f32_16x16x32_bf16(
                            a[kc], FRAG(wmreg, tt * 4 + kc, lane), acc[g][tt], 0, 0, 0);
            }
        }
    }

#pragma unroll
    for (int g = 0; g < MAXG; g++) {
        if (g < ng) {
            int to[4];
#pragma unroll
            for (int r4 = 0; r4 < 4; r4++) {
                int e = tile[g] * 64 + w * 16 + quad * 4 + r4;
                to[r4] = (e < E) ? tgti[e] : -1;
            }
#pragma unroll
            for (int tt = 0; tt < 8; tt++) {
                int c = tt * 16 + n16;
                float bias = mnb0[c];
#pragma unroll
                for (int r4 = 0; r4 < 4; r4++) {
                    if (to[r4] >= 0)
                        atomicAdd(&nfn[(size_t)to[r4] * ND + c],
                                  fmaxf(acc[g][tt][r4] + bias, 0.f));
                }
            }
        }
    }
}

// classify (unchanged from r11).
__global__ __launch_bounds__(256) void classify_k(
    const unsigned short* __restrict__ ef_bf,
    const unsigned short* __restrict__ cw0T, const float* __restrict__ cb0,
    const float* __restrict__ cw1, const float* __restrict__ cb1,
    const float* __restrict__ cw2, const float* __restrict__ cb2,
    float* __restrict__ out, int E)
{
    const int t = threadIdx.x;
    const int e0 = blockIdx.x * TM;
    __shared__ unsigned short h0_bf[TM][66];
    __shared__ float h1[TM][33];

    const int w = t >> 6, lane = t & 63, quad = lane >> 4, n16 = lane & 15;
    const int m = w & 1;
    const int erow = m * 16 + n16;
    int ec = e0 + erow; if (ec >= E) ec = E - 1;
    const unsigned short* pa = ef_bf + (size_t)ec * ED + quad * 8;

    {
        const int cb = (w >> 1) * 32;
        float4_ acc0 = {0.f, 0.f, 0.f, 0.f}, acc1 = acc0;
        const unsigned short* b0p = cw0T + (size_t)(cb + n16) * 128 + quad * 8;
        const unsigned short* b1p = b0p + (size_t)16 * 128;
#pragma unroll
        for (int kc = 0; kc < 4; kc++) {
            short8 a  = *(const short8*)(pa + kc * 32);
            short8 bb0 = *(const short8*)(b0p + kc * 32);
            short8 bb1 = *(const short8*)(b1p + kc * 32);
            acc0 = __builtin_amdgcn_mfma_f32_16x16x32_bf16(a, bb0, acc0, 0, 0, 0);
            acc1 = __builtin_amdgcn_mfma_f32_16x16x32_bf16(a, bb1, acc1, 0, 0, 0);
        }
#pragma unroll
        for (int t2 = 0; t2 < 2; t2++) {
            int c = cb + t2 * 16 + n16;
            float bias = cb0[c];
            float4_ ac = t2 ? acc1 : acc0;
#pragma unroll
            for (int r4 = 0; r4 < 4; r4++)
                h0_bf[m * 16 + quad * 4 + r4][c] = f2bf(fmaxf(ac[r4] + bias, 0.f));
        }
    }
    __syncthreads();

    {
        int c = t & 31;
        int rbase = (t >> 5) * 4;
#pragma unroll
        for (int q = 0; q < 4; q++) {
            int r = rbase + q;
            float acc = cb1[c];
#pragma unroll 8
            for (int k = 0; k < 64; k++) acc += bf2f(h0_bf[r][k]) * cw1[k * 32 + c];
            h1[r][c] = fmaxf(acc, 0.f);
        }
    }
    __syncthreads();

    if (t < TM) {
        int e = e0 + t;
        if (e < E) {
            float a = cb2[0];
#pragma unroll
            for (int k = 0; k < 32; k++) a += h1[t][k] * cw2[k];
            out[e] = a;
        }
    }
}

extern "C" void kernel_launch(void* const* d_in, const int* in_sizes, int n_in,
                              void* d_out, int out_size, void* d_ws, size_t ws_size,
                              hipStream_t stream)
{
    const float* x    = (const float*)d_in[0];
    const float* ea   = (const float*)d_in[1];
    const int*   eidx = (const int*)d_in[2];
    const float* new0 = (const float*)d_in[3];  const float* neb0 = (const float*)d_in[4];
    const float* new1 = (const float*)d_in[5];  const float* neb1 = (const float*)d_in[6];
    const float* eew0 = (const float*)d_in[7];  const float* eeb0 = (const float*)d_in[8];
    const float* eew1 = (const float*)d_in[9];  const float* eeb1 = (const float*)d_in[10];
    const float* mew0 = (const float*)d_in[11]; const float* meb0 = (const float*)d_in[12];
    const float* mew1 = (const float*)d_in[13]; const float* meb1 = (const float*)d_in[14];
    const float* mnw0 = (const float*)d_in[15]; const float* mnb0 = (const float*)d_in[16];
    const float* cw0  = (const float*)d_in[17]; const float* cb0  = (const float*)d_in[18];
    const float* cw1  = (const float*)d_in[19]; const float* cb1  = (const float*)d_in[20];
    const float* cw2  = (const float*)d_in[21]; const float* cb2  = (const float*)d_in[22];

    const int N = in_sizes[0] / NIN;   // 20000
    const int E = in_sizes[2] / 2;     // 100000
    const int* srcj = eidx;            // edge_index[0] = j (source)
    const int* tgti = eidx + E;        // edge_index[1] = i (target)

    char* wsb = (char*)d_ws;
    float* nfn = (float*)wsb;                               // N*ND fp32 accum
    unsigned short* nf0_bf = (unsigned short*)(nfn + (size_t)N * ND);
    unsigned short* nf_bf  = nf0_bf + (size_t)N * ND;
    unsigned short* ef0_bf = nf_bf + (size_t)N * ND;
    unsigned short* ef_bf  = ef0_bf + (size_t)E * ED;
    unsigned short* w0T  = ef_bf + (size_t)E * ED;          // [64][768]
    unsigned short* w1T  = w0T + 49152;                     // [128][64]
    unsigned short* wmT  = w1T + 8192;                      // [128][384]
    unsigned short* w0eT = wmT + 49152;                     // [64][KPAD]
    unsigned short* w1eT = w0eT + 64 * KPAD;                // [128][64]
    unsigned short* cw0T = w1eT + 8192;                     // [64][128]
    unsigned short* w0nT = cw0T + 8192;                     // [128][128]
    unsigned short* w1nT = w0nT + 16384;                    // [128][128]

    const int eblocks32 = (E + TM - 1) / TM;
    const int nblocks32 = (N + TM - 1) / TM;
    const int ntiles = (E + 63) / 64;

    wprep_k<<<(176128 + 255) / 256, 256, 0, stream>>>(mew0, mew1, mnw0, eew0, eew1, cw0,
                                                      new0, new1,
                                                      w0T, w1T, wmT, w0eT, w1eT, cw0T,
                                                      w0nT, w1nT);
    node_embed_k<<<nblocks32, 256, 0, stream>>>(x, w0nT, neb0, w1nT, neb1,
                                                nf0_bf, nf_bf, N);
    edge_embed_k<<<eblocks32, 256, 0, stream>>>(ea, w0eT, eeb0, w1eT, eeb1,
                                                ef0_bf, ef_bf, E);

    const int n4 = (N * ND) / 4;
    const int zgrid = (n4 + 255) / 256;
    zero_k<<<zgrid, 256, 0, stream>>>(nfn, n4);

    for (int s = 0; s < 4; s++) {
        step_a_k<<<GSB, 256, 0, stream>>>(srcj, tgti, nf0_bf, nf_bf, ef0_bf, ef_bf,
                                          w0T, meb0, w1T, meb1, E, ntiles);
        step_b_k<<<GSB, 256, 0, stream>>>(srcj, tgti, nf0_bf, nf_bf, ef_bf, nfn,
                                          wmT, mnb0, E, ntiles);
        f2bfz_k<<<zgrid, 256, 0, stream>>>(nfn, nf_bf, n4);
    }

    classify_k<<<eblocks32, 256, 0, stream>>>(ef_bf, cw0T, cb0, cw1, cb1, cw2, cb2,
                                              (float*)d_out, E);
}

// Round 13
// 787.919 us; speedup vs baseline: 1.0797x; 1.0797x over previous
//
#include <hip/hip_runtime.h>
#include <hip/hip_bf16.h>

#define ND 128
#define ED 128
#define NIN 128
#define EIN 291
#define KPAD 320   // EIN padded to multiple of 32
#define HH 64
#define TM 32      // nodes per block in node-embed / edges per block in classify
#define TS 64      // edges per block in edge_step
#define GSE 768    // grid blocks for edge_embed (3 per CU)
#define MAXGE 3    // max 64-edge tiles per edge_embed block

typedef __attribute__((ext_vector_type(8))) short short8;
typedef __attribute__((ext_vector_type(4))) float float4_;

__device__ __forceinline__ unsigned short f2bf(float f)
{
    union { float f; unsigned u; } v; v.f = f;
    unsigned u = v.u;
    unsigned r = (u + 0x7FFFu + ((u >> 16) & 1u)) >> 16;  // RNE
    return (unsigned short)r;
}
__device__ __forceinline__ float bf2f(unsigned short s)
{
    union { unsigned u; float f; } v; v.u = ((unsigned)s) << 16;
    return v.f;
}

// Stage T N-tiles x KC k-chunks of B (layout [col][K], bf16) into LDS in MFMA
// FRAGMENT ORDER: fragment f=tt*KC+kc occupies 64 consecutive short8 slots.
template<int T, int KC, int K>
__device__ __forceinline__ void stage_frags(const unsigned short* __restrict__ src,
                                            unsigned short* __restrict__ wreg,
                                            int t, int k0)
{
    constexpr int TOT = T * KC * 64;
#pragma unroll
    for (int it = 0; it < TOT / 256; it++) {
        int idx = it * 256 + t;
        int f = idx >> 6, l = idx & 63;
        int col = (f / KC) * 16 + (l & 15);
        int k = (f % KC) * 32 + ((l >> 4) * 8);
        *(short8*)&wreg[idx * 8] = *(const short8*)&src[(size_t)col * K + k0 + k];
    }
}
#define FRAG(wreg, f, lane) (*(const short8*)&(wreg)[(((f) << 6) + (lane)) * 8])

// Zero a float buffer.
__global__ __launch_bounds__(256) void zero_k(float* __restrict__ p, int n4)
{
    int idx = blockIdx.x * 256 + threadIdx.x;
    if (idx < n4) ((float4*)p)[idx] = make_float4(0.f, 0.f, 0.f, 0.f);
}

// Fused: convert fp32 accumulator -> bf16 activations, then zero the accumulator.
__global__ __launch_bounds__(256) void f2bfz_k(float* __restrict__ src,
                                               unsigned short* __restrict__ dst, int n4)
{
    int idx = blockIdx.x * 256 + threadIdx.x;
    if (idx < n4) {
        float4 v = ((const float4*)src)[idx];
        unsigned lo = (unsigned)f2bf(v.x) | ((unsigned)f2bf(v.y) << 16);
        unsigned hi = (unsigned)f2bf(v.z) | ((unsigned)f2bf(v.w) << 16);
        ((uint2*)dst)[idx] = make_uint2(lo, hi);
        ((float4*)src)[idx] = make_float4(0.f, 0.f, 0.f, 0.f);
    }
}

// One-time weight prep: transpose + fp32->bf16 (+ zero-pad K for edge-embed L1).
__global__ __launch_bounds__(256) void wprep_k(
    const float* __restrict__ mew0, const float* __restrict__ mew1, const float* __restrict__ mnw0,
    const float* __restrict__ eew0, const float* __restrict__ eew1, const float* __restrict__ cw0,
    const float* __restrict__ new0, const float* __restrict__ new1,
    unsigned short* __restrict__ w0T, unsigned short* __restrict__ w1T,
    unsigned short* __restrict__ wmT, unsigned short* __restrict__ w0eT,
    unsigned short* __restrict__ w1eT, unsigned short* __restrict__ cw0T,
    unsigned short* __restrict__ w0nT, unsigned short* __restrict__ w1nT)
{
    int idx = blockIdx.x * 256 + threadIdx.x;
    if (idx < 49152) {
        int c = idx / 768, k = idx % 768;
        w0T[idx] = f2bf(mew0[k * 64 + c]);
    } else if (idx < 57344) {
        int j = idx - 49152; int c = j / 64, k = j % 64;
        w1T[j] = f2bf(mew1[k * 128 + c]);
    } else if (idx < 106496) {
        int j = idx - 57344; int c = j / 384, k = j % 384;
        wmT[j] = f2bf(mnw0[k * 128 + c]);
    } else if (idx < 126976) {
        int j = idx - 106496; int c = j / KPAD, k = j % KPAD;
        w0eT[j] = (k < EIN) ? f2bf(eew0[k * 64 + c]) : (unsigned short)0;
    } else if (idx < 135168) {
        int j = idx - 126976; int c = j / 64, k = j % 64;
        w1eT[j] = f2bf(eew1[k * 128 + c]);
    } else if (idx < 143360) {
        int j = idx - 135168; int c = j / 128, k = j % 128;
        cw0T[j] = f2bf(cw0[k * 64 + c]);
    } else if (idx < 159744) {
        int j = idx - 143360; int c = j / 128, k = j % 128;
        w0nT[j] = f2bf(new0[k * 128 + c]);
    } else if (idx < 176128) {
        int j = idx - 159744; int c = j / 128, k = j % 128;
        w1nT[j] = f2bf(new1[k * 128 + c]);
    }
}

// MFMA node embed: 32 nodes/block (unchanged).
__global__ __launch_bounds__(256) void node_embed_k(
    const float* __restrict__ x,
    const unsigned short* __restrict__ w0nT, const float* __restrict__ b0,
    const unsigned short* __restrict__ w1nT, const float* __restrict__ b1,
    unsigned short* __restrict__ nf0_bf, unsigned short* __restrict__ nf_bf, int N)
{
    const int t = threadIdx.x;
    const int n0 = blockIdx.x * TM;
    __shared__ unsigned short wreg[8192];
    __shared__ unsigned short xin[TM][130];
    __shared__ unsigned short h_bf[TM][130];

#pragma unroll
    for (int it = 0; it < 4; it++) {
        int idx = it * 256 + t;
        int r = idx >> 5, c4 = idx & 31;
        int node = n0 + r; if (node >= N) node = N - 1;
        float4 v = *(const float4*)(x + (size_t)node * NIN + c4 * 4);
        unsigned lo = (unsigned)f2bf(v.x) | ((unsigned)f2bf(v.y) << 16);
        unsigned hi = (unsigned)f2bf(v.z) | ((unsigned)f2bf(v.w) << 16);
        *(uint2*)&xin[r][c4 * 4] = make_uint2(lo, hi);
    }

    const int w = t >> 6, lane = t & 63, quad = lane >> 4, n16 = lane & 15;
    const int m = w & 1, nh = w >> 1;

    float4_ acc[4];
#pragma unroll
    for (int q = 0; q < 4; q++) acc[q] = (float4_){0.f, 0.f, 0.f, 0.f};
#pragma unroll
    for (int hf = 0; hf < 2; hf++) {
        stage_frags<8, 2, 128>(w0nT, wreg, t, hf * 64);
        __syncthreads();
#pragma unroll
        for (int kc = 0; kc < 2; kc++) {
            short8 a = *(const short8*)&xin[m * 16 + n16][hf * 64 + kc * 32 + quad * 8];
#pragma unroll
            for (int tt = 0; tt < 4; tt++) {
                short8 b = FRAG(wreg, (nh * 4 + tt) * 2 + kc, lane);
                acc[tt] = __builtin_amdgcn_mfma_f32_16x16x32_bf16(a, b, acc[tt], 0, 0, 0);
            }
        }
        __syncthreads();
    }
#pragma unroll
    for (int tt = 0; tt < 4; tt++) {
        int c = nh * 64 + tt * 16 + n16;
        float bias = b0[c];
#pragma unroll
        for (int r4 = 0; r4 < 4; r4++)
            h_bf[m * 16 + quad * 4 + r4][c] = f2bf(fmaxf(acc[tt][r4] + bias, 0.f));
    }
    __syncthreads();

    float4_ acc2[4];
#pragma unroll
    for (int q = 0; q < 4; q++) acc2[q] = (float4_){0.f, 0.f, 0.f, 0.f};
#pragma unroll
    for (int hf = 0; hf < 2; hf++) {
        stage_frags<8, 2, 128>(w1nT, wreg, t, hf * 64);
        __syncthreads();
#pragma unroll
        for (int kc = 0; kc < 2; kc++) {
            short8 a = *(const short8*)&h_bf[m * 16 + n16][hf * 64 + kc * 32 + quad * 8];
#pragma unroll
            for (int tt = 0; tt < 4; tt++) {
                short8 b = FRAG(wreg, (nh * 4 + tt) * 2 + kc, lane);
                acc2[tt] = __builtin_amdgcn_mfma_f32_16x16x32_bf16(a, b, acc2[tt], 0, 0, 0);
            }
        }
        __syncthreads();
    }
#pragma unroll
    for (int tt = 0; tt < 4; tt++) {
        int c = nh * 64 + tt * 16 + n16;
        float bias = b1[c];
#pragma unroll
        for (int r4 = 0; r4 < 4; r4++) {
            int row = m * 16 + quad * 4 + r4;
            int node = n0 + row;
            if (node < N) {
                unsigned short v = f2bf(acc2[tt][r4] + bias);
                nf0_bf[(size_t)node * ND + c] = v;
                nf_bf[(size_t)node * ND + c] = v;
            }
        }
    }
}

// MFMA edge embed v2: 64 edges/block, 4 waves (wave = 16-edge M-tile, full N).
// Grid-stride MAXGE tiles/block. w1e persistent (16KB); w0e staged in two
// K=160 halves (20KB region, frag order). A-fragments converted fp32->bf16
// directly in registers (clean float4 loads; tail k>=288 masked). Per-wave
// hsl slice -> no per-tile barriers (4 barriers/block total).
__global__ __launch_bounds__(256, 3) void edge_embed_k(
    const float* __restrict__ ea,
    const unsigned short* __restrict__ w0eT, const float* __restrict__ b0,
    const unsigned short* __restrict__ w1eT, const float* __restrict__ b1,
    unsigned short* __restrict__ ef0_bf, unsigned short* __restrict__ ef_bf,
    int E, int ntiles)
{
    const int t = threadIdx.x;
    __shared__ unsigned short w0reg[10240];   // 20KB: one K-half (T=4, KC=5)
    __shared__ unsigned short w1reg[8192];    // 16KB: w1e full (T=8, KC=2)
    __shared__ unsigned short hsl[4][16 * 66];

    const int w = t >> 6, lane = t & 63, quad = lane >> 4, n16 = lane & 15;

    stage_frags<8, 2, 64>(w1eT, w1reg, t, 0);   // covered by first barrier below

    int ng = 0;
    int tile[MAXGE];
#pragma unroll
    for (int g = 0; g < MAXGE; g++) {
        int tl = blockIdx.x + g * GSE;
        if (tl < ntiles) { tile[g] = tl; ng = g + 1; }
        else tile[g] = 0;
    }

    float4_ accL[MAXGE][4];
#pragma unroll
    for (int g = 0; g < MAXGE; g++)
#pragma unroll
        for (int q = 0; q < 4; q++) accL[g][q] = (float4_){0.f, 0.f, 0.f, 0.f};

#pragma unroll
    for (int hf = 0; hf < 2; hf++) {
        __syncthreads();
        stage_frags<4, 5, KPAD>(w0eT, w0reg, t, hf * 160);
        __syncthreads();
#pragma unroll
        for (int g = 0; g < MAXGE; g++) {
            if (g < ng) {
                int e = tile[g] * 64 + w * 16 + n16; if (e >= E) e = E - 1;
                const float* src = ea + (size_t)e * EIN;
#pragma unroll
                for (int kc = 0; kc < 5; kc++) {
                    int k = hf * 160 + kc * 32 + quad * 8;
                    union { short8 s; uint4 u; } av;
                    if (k + 8 <= EIN) {
                        float4 v0 = *(const float4*)(src + k);
                        float4 v1 = *(const float4*)(src + k + 4);
                        av.u.x = (unsigned)f2bf(v0.x) | ((unsigned)f2bf(v0.y) << 16);
                        av.u.y = (unsigned)f2bf(v0.z) | ((unsigned)f2bf(v0.w) << 16);
                        av.u.z = (unsigned)f2bf(v1.x) | ((unsigned)f2bf(v1.y) << 16);
                        av.u.w = (unsigned)f2bf(v1.z) | ((unsigned)f2bf(v1.w) << 16);
                    } else {
                        unsigned short vv[8];
#pragma unroll
                        for (int j = 0; j < 8; j++)
                            vv[j] = (k + j < EIN) ? f2bf(src[k + j]) : (unsigned short)0;
                        av.u.x = (unsigned)vv[0] | ((unsigned)vv[1] << 16);
                        av.u.y = (unsigned)vv[2] | ((unsigned)vv[3] << 16);
                        av.u.z = (unsigned)vv[4] | ((unsigned)vv[5] << 16);
                        av.u.w = (unsigned)vv[6] | ((unsigned)vv[7] << 16);
                    }
#pragma unroll
                    for (int tt = 0; tt < 4; tt++) {
                        short8 b = FRAG(w0reg, tt * 5 + kc, lane);
                        accL[g][tt] = __builtin_amdgcn_mfma_f32_16x16x32_bf16(av.s, b, accL[g][tt], 0, 0, 0);
                    }
                }
            }
        }
    }

    // epilogue per tile: bias+ReLU -> per-wave hsl (C->A transform), then L2
#pragma unroll
    for (int g = 0; g < MAXGE; g++) {
        if (g < ng) {
#pragma unroll
            for (int tt = 0; tt < 4; tt++) {
                int c = tt * 16 + n16;
                float bias = b0[c];
#pragma unroll
                for (int r4 = 0; r4 < 4; r4++)
                    hsl[w][(quad * 4 + r4) * 66 + c] = f2bf(fmaxf(accL[g][tt][r4] + bias, 0.f));
            }
            float4_ acc2[8];
#pragma unroll
            for (int q = 0; q < 8; q++) acc2[q] = (float4_){0.f, 0.f, 0.f, 0.f};
#pragma unroll
            for (int kc = 0; kc < 2; kc++) {
                short8 a2 = *(const short8*)&hsl[w][n16 * 66 + kc * 32 + quad * 8];
#pragma unroll
                for (int tt = 0; tt < 8; tt++)
                    acc2[tt] = __builtin_amdgcn_mfma_f32_16x16x32_bf16(
                        a2, FRAG(w1reg, tt * 2 + kc, lane), acc2[tt], 0, 0, 0);
            }
#pragma unroll
            for (int tt = 0; tt < 8; tt++) {
                int c = tt * 16 + n16;
                float bias = b1[c];
#pragma unroll
                for (int r4 = 0; r4 < 4; r4++) {
                    int e = tile[g] * 64 + w * 16 + quad * 4 + r4;
                    if (e < E) {
                        unsigned short v = f2bf(acc2[tt][r4] + bias);  // no ReLU
                        ef0_bf[(size_t)e * ED + c] = v;
                        ef_bf[(size_t)e * ED + c] = v;
                    }
                }
            }
        }
    }
}

// MFMA MPN step (r11 fused version): 64 edges/block, 4 waves; wave = one
// 16-edge M-tile, full N. Weights fragment-staged in K-sixths (w0, wm) /
// full (w1) through a 16.4KB region; single A-gather reused across phases.
__global__ __launch_bounds__(256, 3) void edge_step_k(
    const int* __restrict__ srcj, const int* __restrict__ tgti,
    const unsigned short* __restrict__ nf0_bf, const unsigned short* __restrict__ nf_bf,
    const unsigned short* __restrict__ ef0_bf, unsigned short* __restrict__ ef_bf,
    float* __restrict__ nfn,
    const unsigned short* __restrict__ w0T, const float* __restrict__ meb0,
    const unsigned short* __restrict__ w1T, const float* __restrict__ meb1,
    const unsigned short* __restrict__ wmT, const float* __restrict__ mnb0, int E)
{
    const int t = threadIdx.x;
    const int e0 = blockIdx.x * TS;
    __shared__ unsigned short wreg[8192];
    __shared__ unsigned short h_bf[TS][66];
    __shared__ unsigned short efn_bf[TS][130];
    __shared__ int sidx[TS];

    if (t < TS) { int e = e0 + t; if (e >= E) e = E - 1; sidx[t] = tgti[e]; }

    const int w = t >> 6, lane = t & 63, quad = lane >> 4, n16 = lane & 15;
    const int erow = w * 16 + n16;
    int ec = e0 + erow; if (ec >= E) ec = E - 1;
    const int ti = tgti[ec], sj = srcj[ec];

    short8 areg[24];
    {
        const unsigned short* pAs[6] = {
            nf0_bf + (size_t)ti * ND + quad * 8,
            nf_bf  + (size_t)ti * ND + quad * 8,
            nf0_bf + (size_t)sj * ND + quad * 8,
            nf_bf  + (size_t)sj * ND + quad * 8,
            ef0_bf + (size_t)ec * ED + quad * 8,
            ef_bf  + (size_t)ec * ED + quad * 8 };
#pragma unroll
        for (int f = 0; f < 24; f++)
            areg[f] = *(const short8*)(pAs[f >> 2] + (f & 3) * 32);
    }

    float4_ accL[4];
#pragma unroll
    for (int q = 0; q < 4; q++) accL[q] = (float4_){0.f, 0.f, 0.f, 0.f};
#pragma unroll
    for (int hf = 0; hf < 6; hf++) {
        stage_frags<4, 4, 768>(w0T, wreg, t, hf * 128);
        __syncthreads();
#pragma unroll
        for (int kc = 0; kc < 4; kc++) {
#pragma unroll
            for (int tt = 0; tt < 4; tt++) {
                short8 b = FRAG(wreg, tt * 4 + kc, lane);
                accL[tt] = __builtin_amdgcn_mfma_f32_16x16x32_bf16(areg[hf * 4 + kc], b, accL[tt], 0, 0, 0);
            }
        }
        __syncthreads();
    }
#pragma unroll
    for (int tt = 0; tt < 4; tt++) {
        int c = tt * 16 + n16;
        float bias = meb0[c];
#pragma unroll
        for (int r4 = 0; r4 < 4; r4++)
            h_bf[w * 16 + quad * 4 + r4][c] = f2bf(fmaxf(accL[tt][r4] + bias, 0.f));
    }
    __syncthreads();

    stage_frags<8, 2, 64>(w1T, wreg, t, 0);
    __syncthreads();
    {
        float4_ acc[8];
#pragma unroll
        for (int q = 0; q < 8; q++) acc[q] = (float4_){0.f, 0.f, 0.f, 0.f};
#pragma unroll
        for (int kc = 0; kc < 2; kc++) {
            short8 a = *(const short8*)&h_bf[w * 16 + n16][kc * 32 + quad * 8];
#pragma unroll
            for (int tt = 0; tt < 8; tt++) {
                short8 b = FRAG(wreg, tt * 2 + kc, lane);
                acc[tt] = __builtin_amdgcn_mfma_f32_16x16x32_bf16(a, b, acc[tt], 0, 0, 0);
            }
        }
#pragma unroll
        for (int tt = 0; tt < 8; tt++) {
            int c = tt * 16 + n16;
            float bias = meb1[c];
#pragma unroll
            for (int r4 = 0; r4 < 4; r4++) {
                int row = w * 16 + quad * 4 + r4;
                unsigned short v = f2bf(fmaxf(acc[tt][r4] + bias, 0.f));
                efn_bf[row][c] = v;
                int e = e0 + row;
                if (e < E) ef_bf[(size_t)e * ED + c] = v;
            }
        }
    }
    __syncthreads();

    float4_ accM[8];
#pragma unroll
    for (int q = 0; q < 8; q++) accM[q] = (float4_){0.f, 0.f, 0.f, 0.f};
#pragma unroll
    for (int hf = 0; hf < 6; hf++) {
        stage_frags<8, 2, 384>(wmT, wreg, t, hf * 64);
        __syncthreads();
#pragma unroll
        for (int kc = 0; kc < 2; kc++) {
            int kk = hf * 2 + kc;
            short8 a;
            if (kk < 8) a = areg[kk];
            else        a = *(const short8*)&efn_bf[erow][(kk - 8) * 32 + quad * 8];
#pragma unroll
            for (int tt = 0; tt < 8; tt++) {
                short8 b = FRAG(wreg, tt * 2 + kc, lane);
                accM[tt] = __builtin_amdgcn_mfma_f32_16x16x32_bf16(a, b, accM[tt], 0, 0, 0);
            }
        }
        __syncthreads();
    }
#pragma unroll
    for (int tt = 0; tt < 8; tt++) {
        int c = tt * 16 + n16;
        float bias = mnb0[c];
#pragma unroll
        for (int r4 = 0; r4 < 4; r4++) {
            int row = w * 16 + quad * 4 + r4;
            int e = e0 + row;
            if (e < E)
                atomicAdd(&nfn[(size_t)sidx[row] * ND + c],
                          fmaxf(accM[tt][r4] + bias, 0.f));
        }
    }
}

// classify (unchanged).
__global__ __launch_bounds__(256) void classify_k(
    const unsigned short* __restrict__ ef_bf,
    const unsigned short* __restrict__ cw0T, const float* __restrict__ cb0,
    const float* __restrict__ cw1, const float* __restrict__ cb1,
    const float* __restrict__ cw2, const float* __restrict__ cb2,
    float* __restrict__ out, int E)
{
    const int t = threadIdx.x;
    const int e0 = blockIdx.x * TM;
    __shared__ unsigned short h0_bf[TM][66];
    __shared__ float h1[TM][33];

    const int w = t >> 6, lane = t & 63, quad = lane >> 4, n16 = lane & 15;
    const int m = w & 1;
    const int erow = m * 16 + n16;
    int ec = e0 + erow; if (ec >= E) ec = E - 1;
    const unsigned short* pa = ef_bf + (size_t)ec * ED + quad * 8;

    {
        const int cb = (w >> 1) * 32;
        float4_ acc0 = {0.f, 0.f, 0.f, 0.f}, acc1 = acc0;
        const unsigned short* b0p = cw0T + (size_t)(cb + n16) * 128 + quad * 8;
        const unsigned short* b1p = b0p + (size_t)16 * 128;
#pragma unroll
        for (int kc = 0; kc < 4; kc++) {
            short8 a  = *(const short8*)(pa + kc * 32);
            short8 bb0 = *(const short8*)(b0p + kc * 32);
            short8 bb1 = *(const short8*)(b1p + kc * 32);
            acc0 = __builtin_amdgcn_mfma_f32_16x16x32_bf16(a, bb0, acc0, 0, 0, 0);
            acc1 = __builtin_amdgcn_mfma_f32_16x16x32_bf16(a, bb1, acc1, 0, 0, 0);
        }
#pragma unroll
        for (int t2 = 0; t2 < 2; t2++) {
            int c = cb + t2 * 16 + n16;
            float bias = cb0[c];
            float4_ ac = t2 ? acc1 : acc0;
#pragma unroll
            for (int r4 = 0; r4 < 4; r4++)
                h0_bf[m * 16 + quad * 4 + r4][c] = f2bf(fmaxf(ac[r4] + bias, 0.f));
        }
    }
    __syncthreads();

    {
        int c = t & 31;
        int rbase = (t >> 5) * 4;
#pragma unroll
        for (int q = 0; q < 4; q++) {
            int r = rbase + q;
            float acc = cb1[c];
#pragma unroll 8
            for (int k = 0; k < 64; k++) acc += bf2f(h0_bf[r][k]) * cw1[k * 32 + c];
            h1[r][c] = fmaxf(acc, 0.f);
        }
    }
    __syncthreads();

    if (t < TM) {
        int e = e0 + t;
        if (e < E) {
            float a = cb2[0];
#pragma unroll
            for (int k = 0; k < 32; k++) a += h1[t][k] * cw2[k];
            out[e] = a;
        }
    }
}

extern "C" void kernel_launch(void* const* d_in, const int* in_sizes, int n_in,
                              void* d_out, int out_size, void* d_ws, size_t ws_size,
                              hipStream_t stream)
{
    const float* x    = (const float*)d_in[0];
    const float* ea   = (const float*)d_in[1];
    const int*   eidx = (const int*)d_in[2];
    const float* new0 = (const float*)d_in[3];  const float* neb0 = (const float*)d_in[4];
    const float* new1 = (const float*)d_in[5];  const float* neb1 = (const float*)d_in[6];
    const float* eew0 = (const float*)d_in[7];  const float* eeb0 = (const float*)d_in[8];
    const float* eew1 = (const float*)d_in[9];  const float* eeb1 = (const float*)d_in[10];
    const float* mew0 = (const float*)d_in[11]; const float* meb0 = (const float*)d_in[12];
    const float* mew1 = (const float*)d_in[13]; const float* meb1 = (const float*)d_in[14];
    const float* mnw0 = (const float*)d_in[15]; const float* mnb0 = (const float*)d_in[16];
    const float* cw0  = (const float*)d_in[17]; const float* cb0  = (const float*)d_in[18];
    const float* cw1  = (const float*)d_in[19]; const float* cb1  = (const float*)d_in[20];
    const float* cw2  = (const float*)d_in[21]; const float* cb2  = (const float*)d_in[22];

    const int N = in_sizes[0] / NIN;   // 20000
    const int E = in_sizes[2] / 2;     // 100000
    const int* srcj = eidx;            // edge_index[0] = j (source)
    const int* tgti = eidx + E;        // edge_index[1] = i (target)

    char* wsb = (char*)d_ws;
    float* nfn = (float*)wsb;                               // N*ND fp32 accum
    unsigned short* nf0_bf = (unsigned short*)(nfn + (size_t)N * ND);
    unsigned short* nf_bf  = nf0_bf + (size_t)N * ND;
    unsigned short* ef0_bf = nf_bf + (size_t)N * ND;
    unsigned short* ef_bf  = ef0_bf + (size_t)E * ED;
    unsigned short* w0T  = ef_bf + (size_t)E * ED;          // [64][768]
    unsigned short* w1T  = w0T + 49152;                     // [128][64]
    unsigned short* wmT  = w1T + 8192;                      // [128][384]
    unsigned short* w0eT = wmT + 49152;                     // [64][KPAD]
    unsigned short* w1eT = w0eT + 64 * KPAD;                // [128][64]
    unsigned short* cw0T = w1eT + 8192;                     // [64][128]
    unsigned short* w0nT = cw0T + 8192;                     // [128][128]
    unsigned short* w1nT = w0nT + 16384;                    // [128][128]

    const int eblocks32 = (E + TM - 1) / TM;
    const int nblocks32 = (N + TM - 1) / TM;
    const int ntiles64 = (E + 63) / 64;

    wprep_k<<<(176128 + 255) / 256, 256, 0, stream>>>(mew0, mew1, mnw0, eew0, eew1, cw0,
                                                      new0, new1,
                                                      w0T, w1T, wmT, w0eT, w1eT, cw0T,
                                                      w0nT, w1nT);
    node_embed_k<<<nblocks32, 256, 0, stream>>>(x, w0nT, neb0, w1nT, neb1,
                                                nf0_bf, nf_bf, N);
    edge_embed_k<<<GSE, 256, 0, stream>>>(ea, w0eT, eeb0, w1eT, eeb1,
                                          ef0_bf, ef_bf, E, ntiles64);

    const int n4 = (N * ND) / 4;
    const int zgrid = (n4 + 255) / 256;
    zero_k<<<zgrid, 256, 0, stream>>>(nfn, n4);

    for (int s = 0; s < 4; s++) {
        edge_step_k<<<ntiles64, 256, 0, stream>>>(srcj, tgti, nf0_bf, nf_bf,
                                                  ef0_bf, ef_bf, nfn,
                                                  w0T, meb0, w1T, meb1, wmT, mnb0, E);
        f2bfz_k<<<zgrid, 256, 0, stream>>>(nfn, nf_bf, n4);
    }

    classify_k<<<eblocks32, 256, 0, stream>>>(ef_bf, cw0T, cb0, cw1, cb1, cw2, cb2,
                                              (float*)d_out, E);
}